// Round 15
// baseline (316.477 us; speedup 1.0000x reference)
//
#include <hip/hip_runtime.h>
#include <hip/hip_bf16.h>

#define NIMG 4
#define C    256
#define H    128
#define W    128
#define HW   (H*W)         // 16384
#define CHW  (C*HW)        // 4194304
#define TOT  (NIMG*CHW)    // 16777216 elems per output tensor

typedef short bf16x8 __attribute__((ext_vector_type(8)));
typedef unsigned short ushort8 __attribute__((ext_vector_type(8)));
typedef float f32x16 __attribute__((ext_vector_type(16)));
typedef unsigned short u16;

__device__ inline u16 f2bf(float f) {
    __hip_bfloat16 h = __float2bfloat16(f);
    return __builtin_bit_cast(u16, h);
}

// B-tile swizzle: XOR upper byte-addr bits into the 16B-group bits (4..6).
// Bijective; applied identically on write and read (buffer-local offsets).
__device__ __forceinline__ int swzB(int byte) {
    return byte ^ (((byte >> 7) & 1) << 4) ^ (((byte >> 8) & 3) << 5);
}

// ---------------------------------------------------------------------------
// prep: wcat2 fragment-major layout for coalesced direct A-fragment loads:
// dims [ct 9][tap 9][cq 16][coh 2][lh 2][l31 32][e 8]; wbf = bf16(w_comp)
// ---------------------------------------------------------------------------
__global__ __launch_bounds__(256)
void prep_w_kernel(const float* __restrict__ w_hp, const float* __restrict__ w_res,
                   const float* __restrict__ w_mul, const float* __restrict__ w_comp,
                   u16* __restrict__ wcat, u16* __restrict__ wbf)
{
    int i = blockIdx.x * 256 + threadIdx.x;
    const int NW = 576 * 2304;
    if (i < NW) {
        int e   = i & 7;
        int l31 = (i >> 3) & 31;
        int lhh = (i >> 8) & 1;
        int coh = (i >> 9) & 1;
        int cq  = (i >> 10) & 15;
        int t9  = i >> 14;              // 0..80
        int ct  = t9 / 9;
        int tap = t9 - ct * 9;
        int gco = ct*64 + coh*32 + l31;
        int ci  = cq*16 + lhh*8 + e;
        float v = 0.f;
        if (gco < 9)        v = w_hp[gco * 2304 + ci * 9 + tap];
        else if (gco < 265) v = w_res[(gco - 9) * 2304 + ci * 9 + tap];
        else if (gco < 521) v = w_mul[(gco - 265) * 2304 + ci * 9 + tap];
        wcat[i] = f2bf(v);
    } else if (i < NW + 65536) {
        int j = i - NW;
        wbf[j] = f2bf(w_comp[j]);
    }
}

// ---------------------------------------------------------------------------
// K1: compressed(bf16) = w_comp @ x + b_comp via bf16 MFMA. (unchanged)
// ---------------------------------------------------------------------------
__global__ __launch_bounds__(256)
void conv1x1_mfma_kernel(const float* __restrict__ x, const u16* __restrict__ wbf,
                         const float* __restrict__ b, u16* __restrict__ comp)
{
    __shared__ u16 As[64 * 40];
    __shared__ u16 Bs[256 * 40];

    const int pt  = blockIdx.x;
    const int n   = pt >> 6;
    const int hw0 = (pt & 63) * 256;
    const int co0 = blockIdx.y * 64;

    const int tid  = threadIdx.x;
    const int wv   = tid >> 6;
    const int lane = tid & 63;
    const int l31  = lane & 31;
    const int lh   = lane >> 5;

    f32x16 acc[2][2];
    #pragma unroll
    for (int cf = 0; cf < 2; ++cf)
        #pragma unroll
        for (int p = 0; p < 2; ++p)
            #pragma unroll
            for (int e = 0; e < 16; ++e) acc[cf][p][e] = 0.f;

    for (int c0 = 0; c0 < 256; c0 += 32) {
        #pragma unroll
        for (int r = 0; r < 2; ++r) {
            int l  = tid + 256*r;
            int co = l >> 3, cq = l & 7;
            ushort4 v = *(const ushort4*)(wbf + (co0+co)*256 + c0 + cq*4);
            *(ushort4*)(As + co*40 + cq*4) = v;
        }
        #pragma unroll
        for (int r = 0; r < 2; ++r) {
            int l = tid + 256*r;
            int q = l & 7, g = l >> 3;
            const float* src = x + (long)n*CHW + (long)(c0 + q*4)*HW + hw0 + g*4;
            float4 v0 = *(const float4*)(src);
            float4 v1 = *(const float4*)(src + HW);
            float4 v2 = *(const float4*)(src + 2*HW);
            float4 v3 = *(const float4*)(src + 3*HW);
            u16* dst = Bs + (g*4)*40 + q*4;
            *(ushort4*)(dst)       = make_ushort4(f2bf(v0.x), f2bf(v1.x), f2bf(v2.x), f2bf(v3.x));
            *(ushort4*)(dst + 40)  = make_ushort4(f2bf(v0.y), f2bf(v1.y), f2bf(v2.y), f2bf(v3.y));
            *(ushort4*)(dst + 80)  = make_ushort4(f2bf(v0.z), f2bf(v1.z), f2bf(v2.z), f2bf(v3.z));
            *(ushort4*)(dst + 120) = make_ushort4(f2bf(v0.w), f2bf(v1.w), f2bf(v2.w), f2bf(v3.w));
        }
        __syncthreads();
        #pragma unroll
        for (int kk = 0; kk < 2; ++kk) {
            bf16x8 a0 = *(const bf16x8*)(As + (l31     )*40 + kk*16 + lh*8);
            bf16x8 a1 = *(const bf16x8*)(As + (l31 + 32)*40 + kk*16 + lh*8);
            #pragma unroll
            for (int p = 0; p < 2; ++p) {
                bf16x8 bb = *(const bf16x8*)(Bs + (wv*64 + p*32 + l31)*40 + kk*16 + lh*8);
                acc[0][p] = __builtin_amdgcn_mfma_f32_32x32x16_bf16(a0, bb, acc[0][p], 0, 0, 0);
                acc[1][p] = __builtin_amdgcn_mfma_f32_32x32x16_bf16(a1, bb, acc[1][p], 0, 0, 0);
            }
        }
        __syncthreads();
    }

    #pragma unroll
    for (int cf = 0; cf < 2; ++cf) {
        #pragma unroll
        for (int p = 0; p < 2; ++p) {
            int pos = hw0 + wv*64 + p*32 + l31;
            #pragma unroll
            for (int reg = 0; reg < 16; ++reg) {
                int row = (reg & 3) + 8*(reg >> 2) + 4*lh;
                int co  = co0 + cf*32 + row;
                comp[(long)n*CHW + (long)co*HW + pos] = f2bf(acc[cf][p][reg] + b[co]);
            }
        }
    }
}

// ---------------------------------------------------------------------------
// K2: fused 3x3 convs, bf16 MFMA implicit GEMM.  (r14 + r15 barrier diet)
// block = 64co x 256pos (2 rows), 4 waves of 64co x 64pos, acc[2][2] = 64 AGPR.
// A operands: direct coalesced global loads from wcat2 via 3-deep reg ring.
// B: double-buffered Bs[2][4*132*16], ONE barrier per chunk.
// r15: the barrier is raw s_barrier + lgkmcnt(0) ONLY -- no vmcnt(0) drain
// (pb and A-ring loads are wave-private; compiler dataflow waits cover them).
// s_setprio(1) wraps the MFMA cluster (stage/MFMA role diversity on the SIMD).
// XCD-aware remap: 9 co-tiles of one pos-window back-to-back per XCD.
// ---------------------------------------------------------------------------
__global__ __launch_bounds__(256, 3)
void conv3x3_mfma_kernel(const u16* __restrict__ wcat, const u16* __restrict__ comp,
                         const float* __restrict__ xin,
                         const float* __restrict__ b_hp, const float* __restrict__ b_res,
                         const float* __restrict__ b_mul,
                         float* __restrict__ out, float* __restrict__ filt_raw)
{
    __shared__ u16 Bs[2][4 * 132 * 16];   // 33,792 B

    // ---- XCD-aware remap (2304 blocks, %8==0 -> bijective)
    const int id  = blockIdx.x + 256 * blockIdx.y;
    const int xcd = id & 7;
    const int rr_ = id >> 3;            // 0..287
    const int ct  = rr_ % 9;            // co-tile 0..8
    const int pt  = (xcd << 5) + rr_ / 9; // pos-tile 0..255

    const int n   = pt >> 6;
    const int y0  = (pt & 63) * 2;
    const int co0 = ct * 64;

    const int tid  = threadIdx.x;
    const int wv   = tid >> 6;
    const int lane = tid & 63;
    const int l31  = lane & 31;
    const int lh   = lane >> 5;
    const int row  = wv & 1;            // output row within block
    const int ch   = wv >> 1;           // column half (0/1)

    // zero both buffers (pads + OOB rows stay zero)
    for (int i = tid; i < 2*4*132*16/2; i += 256) ((int*)Bs)[i] = 0;

    f32x16 acc[2][2];
    #pragma unroll
    for (int cf = 0; cf < 2; ++cf)
        #pragma unroll
        for (int p = 0; p < 2; ++p)
            #pragma unroll
            for (int e = 0; e < 16; ++e) acc[cf][p][e] = 0.f;

    // ---- A fragment base (coalesced per wave): frag(tap,c) =
    // wt0 + tap*16384 + c*1024 (+512 for co-half 1)
    const u16* wt0 = wcat + (long)ct*147456 + lh*256 + l31*8;

    // ---- B staging coords: wave wv stages patch row wv (y = y0-1+wv)
    const int byy = y0 - 1 + wv;
    const bool bv = (byy >= 0 && byy < H);
    const u16* bsrc = comp + ((long)n*C + lh*8)*HW + (bv ? byy : 0)*W + l31*4;

    __syncthreads();                      // zero-fill visible

    // prologue: stage chunk 0 into buf0; prefetch chunk 1 into pb
    ushort4 pb[8];
    if (bv) {
        #pragma unroll
        for (int j = 0; j < 8; ++j) pb[j] = *(const ushort4*)(bsrc + (long)j*HW);
        #pragma unroll
        for (int cw = 0; cw < 4; ++cw) {
            ushort8 v;
            #pragma unroll
            for (int j = 0; j < 8; ++j) v[j] = ((const u16*)&pb[j])[cw];
            int byteoff = ((wv*132 + l31*4 + 1 + cw) << 5) + (lh << 4);
            *(ushort8*)((char*)Bs[0] + swzB(byteoff)) = v;
        }
        #pragma unroll
        for (int j = 0; j < 8; ++j) pb[j] = *(const ushort4*)(bsrc + 16*HW + (long)j*HW);
    }
    bf16x8 af0[3], af1[3];
    #pragma unroll
    for (int t = 0; t < 3; ++t) {
        af0[t] = *(const bf16x8*)(wt0 + t*16384);
        af1[t] = *(const bf16x8*)(wt0 + t*16384 + 512);
    }
    __syncthreads();                      // buf0 ready

    for (int c = 0; c < 16; ++c) {
        // ---- stage B(c+1) into the other buffer; overlaps MFMA(c) below
        if (c < 15 && bv) {
            char* dbuf = (char*)Bs[(c + 1) & 1];
            #pragma unroll
            for (int cw = 0; cw < 4; ++cw) {
                ushort8 v;
                #pragma unroll
                for (int j = 0; j < 8; ++j) v[j] = ((const u16*)&pb[j])[cw];
                int byteoff = ((wv*132 + l31*4 + 1 + cw) << 5) + (lh << 4);
                *(ushort8*)(dbuf + swzB(byteoff)) = v;
            }
            if (c < 14) {
                const u16* s = bsrc + (long)(c + 2)*16*HW;
                #pragma unroll
                for (int j = 0; j < 8; ++j) pb[j] = *(const ushort4*)(s + (long)j*HW);
            }
        }
        // ---- MFMA on buf[c&1]: tap t consumes ring slot t%3, reloads with
        // tap t+3 (or chunk c+1's tap t-6). All indices compile-time.
        const char* rbuf = (const char*)Bs[c & 1];
        __builtin_amdgcn_s_setprio(1);
        #pragma unroll
        for (int tap = 0; tap < 9; ++tap) {
            const int kh = tap / 3, kw = tap - kh*3;
            const int r_ = tap % 3;
            bf16x8 a0 = af0[r_], a1 = af1[r_];
            if (tap < 6) {
                af0[r_] = *(const bf16x8*)(wt0 + (tap+3)*16384 + c*1024);
                af1[r_] = *(const bf16x8*)(wt0 + (tap+3)*16384 + c*1024 + 512);
            } else if (c < 15) {
                af0[r_] = *(const bf16x8*)(wt0 + (tap-6)*16384 + (c+1)*1024);
                af1[r_] = *(const bf16x8*)(wt0 + (tap-6)*16384 + (c+1)*1024 + 512);
            }
            #pragma unroll
            for (int p = 0; p < 2; ++p) {
                int byteoff = (((row + kh)*132 + ch*64 + p*32 + l31 + kw) << 5) + (lh << 4);
                bf16x8 bb = *(const bf16x8*)(rbuf + swzB(byteoff));
                acc[0][p] = __builtin_amdgcn_mfma_f32_32x32x16_bf16(a0, bb, acc[0][p], 0, 0, 0);
                acc[1][p] = __builtin_amdgcn_mfma_f32_32x32x16_bf16(a1, bb, acc[1][p], 0, 0, 0);
            }
        }
        __builtin_amdgcn_s_setprio(0);
        // ---- barrier WITHOUT vmcnt drain: LDS visibility only.
        if (c < 15) {
            asm volatile("s_waitcnt lgkmcnt(0)" ::: "memory");
            __builtin_amdgcn_s_barrier();
            __builtin_amdgcn_sched_barrier(0);
        }
    }

    // ---- epilogue: D col = lane&31 (pos), row = (reg&3)+8*(reg>>2)+4*(lane>>5) (co)
    const int yrow = y0 + row;
    #pragma unroll
    for (int cf = 0; cf < 2; ++cf) {
        #pragma unroll
        for (int p = 0; p < 2; ++p) {
            int xx = ch*64 + p*32 + l31;
            #pragma unroll
            for (int reg = 0; reg < 16; ++reg) {
                int rw = (reg & 3) + 8*(reg >> 2) + 4*lh;
                int co = co0 + cf*32 + rw;
                float v = acc[cf][p][reg];
                if (co < 9) {
                    filt_raw[((long)n*9 + co)*HW + yrow*W + xx] = v + b_hp[co];
                } else if (co < 265) {
                    int cc = co - 9;
                    long idx = (long)n*CHW + (long)cc*HW + yrow*W + xx;
                    out[(long)TOT + idx] = xin[idx] + v + b_res[cc];
                } else if (co < 521) {
                    int cc = co - 265;
                    long idx = (long)n*CHW + (long)cc*HW + yrow*W + xx;
                    out[2L*TOT + idx] = xin[idx] * (v + b_mul[cc]);
                }
            }
        }
    }
}

// ---------------------------------------------------------------------------
// K3: softmax*hamming renorm + 3x3 carafe + feat_hp = x - carafe (float4)
// XCD-aware remap (512%8==0).
// ---------------------------------------------------------------------------
__global__ __launch_bounds__(256)
void carafe_hp_kernel(const float* __restrict__ x, const float* __restrict__ filt_raw,
                      const float* __restrict__ ham, float* __restrict__ out)
{
    const int id = blockIdx.x;
    const int pt = ((id & 7) << 6) + (id >> 3);   // xcd*64 + r, bijective on [0,512)
    const int n  = pt >> 7;
    const int y  = pt & 127;
    const int pg = threadIdx.x & 31;
    const int cs = threadIdx.x >> 5;
    const int x0 = pg * 4;

    float4 wt[9];
    {
        const float* fr = filt_raw + (long)n*9*HW + y*W + x0;
        #pragma unroll
        for (int t = 0; t < 9; ++t) wt[t] = *(const float4*)(fr + t*HW);
        float4 mx = wt[0];
        #pragma unroll
        for (int t = 1; t < 9; ++t) {
            mx.x = fmaxf(mx.x, wt[t].x); mx.y = fmaxf(mx.y, wt[t].y);
            mx.z = fmaxf(mx.z, wt[t].z); mx.w = fmaxf(mx.w, wt[t].w);
        }
        float4 s = make_float4(0,0,0,0);
        #pragma unroll
        for (int t = 0; t < 9; ++t) {
            float hm = ham[t];
            wt[t].x = expf(wt[t].x - mx.x) * hm; s.x += wt[t].x;
            wt[t].y = expf(wt[t].y - mx.y) * hm; s.y += wt[t].y;
            wt[t].z = expf(wt[t].z - mx.z) * hm; s.z += wt[t].z;
            wt[t].w = expf(wt[t].w - mx.w) * hm; s.w += wt[t].w;
        }
        float4 inv = make_float4(1.f/s.x, 1.f/s.y, 1.f/s.z, 1.f/s.w);
        #pragma unroll
        for (int t = 0; t < 9; ++t) {
            wt[t].x *= inv.x; wt[t].y *= inv.y; wt[t].z *= inv.z; wt[t].w *= inv.w;
        }
    }

    const float* xb = x   + (long)n*CHW + (long)y*W + x0;
    float*       ob = out + (long)n*CHW + (long)y*W + x0;

    for (int i = 0; i < 32; ++i) {
        int c = cs*32 + i;
        const float* xc = xb + (long)c*HW;
        float rr[3][6];
        #pragma unroll
        for (int dh = 0; dh < 3; ++dh) {
            int yy = y - 1 + dh;
            if (yy >= 0 && yy < H) {
                const float* p = xc + (dh-1)*W;
                float4 v = *(const float4*)p;
                rr[dh][0] = (x0 > 0)     ? p[-1] : 0.f;
                rr[dh][1] = v.x; rr[dh][2] = v.y; rr[dh][3] = v.z; rr[dh][4] = v.w;
                rr[dh][5] = (x0 + 4 < W) ? p[4]  : 0.f;
            } else {
                #pragma unroll
                for (int j = 0; j < 6; ++j) rr[dh][j] = 0.f;
            }
        }
        float4 a = make_float4(0,0,0,0);
        #pragma unroll
        for (int dh = 0; dh < 3; ++dh)
            #pragma unroll
            for (int kw = 0; kw < 3; ++kw) {
                float4 wv = wt[dh*3+kw];
                a.x += wv.x * rr[dh][kw];
                a.y += wv.y * rr[dh][kw+1];
                a.z += wv.z * rr[dh][kw+2];
                a.w += wv.w * rr[dh][kw+3];
            }
        float4 o;
        o.x = rr[1][1] - a.x; o.y = rr[1][2] - a.y;
        o.z = rr[1][3] - a.z; o.w = rr[1][4] - a.w;
        *(float4*)(ob + (long)c*HW) = o;
    }
}

// ---------------------------------------------------------------------------
extern "C" void kernel_launch(void* const* d_in, const int* in_sizes, int n_in,
                              void* d_out, int out_size, void* d_ws, size_t ws_size,
                              hipStream_t stream)
{
    const float* x      = (const float*)d_in[0];
    const float* w_comp = (const float*)d_in[1];
    const float* b_comp = (const float*)d_in[2];
    const float* w_hp   = (const float*)d_in[3];
    const float* b_hp   = (const float*)d_in[4];
    const float* w_res  = (const float*)d_in[5];
    const float* b_res  = (const float*)d_in[6];
    const float* w_mul  = (const float*)d_in[7];
    const float* b_mul  = (const float*)d_in[8];
    const float* ham    = (const float*)d_in[9];
    float* out = (float*)d_out;

    u16*   comp = (u16*)d_ws;
    float* filt = (float*)((char*)d_ws + (size_t)TOT*2);
    u16*   wcat = (u16*)((char*)d_ws + (size_t)TOT*2 + 2359296);
    u16*   wbf  = (u16*)((char*)d_ws + (size_t)TOT*2 + 2359296 + 2654208);

    const int NW = 576*2304;
    prep_w_kernel<<<(NW + 65536 + 255)/256, 256, 0, stream>>>(w_hp, w_res, w_mul, w_comp, wcat, wbf);
    conv1x1_mfma_kernel<<<dim3(256, 4), 256, 0, stream>>>(x, wbf, b_comp, comp);
    conv3x3_mfma_kernel<<<dim3(NIMG*H/2, 9), 256, 0, stream>>>(
        wcat, comp, x, b_hp, b_res, b_mul, out, filt);
    carafe_hp_kernel<<<NIMG*H, 256, 0, stream>>>(x, filt, ham, out);
}

// Round 16
// 306.469 us; speedup vs baseline: 1.0327x; 1.0327x over previous
//
#include <hip/hip_runtime.h>
#include <hip/hip_bf16.h>

#define NIMG 4
#define C    256
#define H    128
#define W    128
#define HW   (H*W)         // 16384
#define CHW  (C*HW)        // 4194304
#define TOT  (NIMG*CHW)    // 16777216 elems per output tensor

typedef short bf16x8 __attribute__((ext_vector_type(8)));
typedef unsigned short ushort8 __attribute__((ext_vector_type(8)));
typedef float f32x16 __attribute__((ext_vector_type(16)));
typedef unsigned short u16;

__device__ inline u16 f2bf(float f) {
    __hip_bfloat16 h = __float2bfloat16(f);
    return __builtin_bit_cast(u16, h);
}

// B-tile swizzle: XOR upper byte-addr bits into the 16B-group bits (4..6).
// Bijective; applied identically on write and read.
__device__ __forceinline__ int swzB(int byte) {
    return byte ^ (((byte >> 7) & 1) << 4) ^ (((byte >> 8) & 3) << 5);
}

// ---------------------------------------------------------------------------
// prep: wcat[576 co][tap*256+ci] (tap-major) from hp/res/mul; wbf = bf16(w_comp)
// (r16: restored to match the restored K2's A-staging layout)
// ---------------------------------------------------------------------------
__global__ __launch_bounds__(256)
void prep_w_kernel(const float* __restrict__ w_hp, const float* __restrict__ w_res,
                   const float* __restrict__ w_mul, const float* __restrict__ w_comp,
                   u16* __restrict__ wcat, u16* __restrict__ wbf)
{
    int i = blockIdx.x * 256 + threadIdx.x;
    const int NW = 576 * 2304;
    if (i < NW) {
        int co = i / 2304, r = i - co * 2304;
        int tap = r >> 8, ci = r & 255;
        float v = 0.f;
        if (co < 9)        v = w_hp[co * 2304 + ci * 9 + tap];
        else if (co < 265) v = w_res[(co - 9) * 2304 + ci * 9 + tap];
        else if (co < 521) v = w_mul[(co - 265) * 2304 + ci * 9 + tap];
        wcat[i] = f2bf(v);
    } else if (i < NW + 65536) {
        int j = i - NW;
        wbf[j] = f2bf(w_comp[j]);
    }
}

// ---------------------------------------------------------------------------
// K1: compressed(bf16) = w_comp @ x + b_comp via bf16 MFMA. (unchanged)
// ---------------------------------------------------------------------------
__global__ __launch_bounds__(256)
void conv1x1_mfma_kernel(const float* __restrict__ x, const u16* __restrict__ wbf,
                         const float* __restrict__ b, u16* __restrict__ comp)
{
    __shared__ u16 As[64 * 40];
    __shared__ u16 Bs[256 * 40];

    const int pt  = blockIdx.x;
    const int n   = pt >> 6;
    const int hw0 = (pt & 63) * 256;
    const int co0 = blockIdx.y * 64;

    const int tid  = threadIdx.x;
    const int wv   = tid >> 6;
    const int lane = tid & 63;
    const int l31  = lane & 31;
    const int lh   = lane >> 5;

    f32x16 acc[2][2];
    #pragma unroll
    for (int cf = 0; cf < 2; ++cf)
        #pragma unroll
        for (int p = 0; p < 2; ++p)
            #pragma unroll
            for (int e = 0; e < 16; ++e) acc[cf][p][e] = 0.f;

    for (int c0 = 0; c0 < 256; c0 += 32) {
        #pragma unroll
        for (int r = 0; r < 2; ++r) {
            int l  = tid + 256*r;
            int co = l >> 3, cq = l & 7;
            ushort4 v = *(const ushort4*)(wbf + (co0+co)*256 + c0 + cq*4);
            *(ushort4*)(As + co*40 + cq*4) = v;
        }
        #pragma unroll
        for (int r = 0; r < 2; ++r) {
            int l = tid + 256*r;
            int q = l & 7, g = l >> 3;
            const float* src = x + (long)n*CHW + (long)(c0 + q*4)*HW + hw0 + g*4;
            float4 v0 = *(const float4*)(src);
            float4 v1 = *(const float4*)(src + HW);
            float4 v2 = *(const float4*)(src + 2*HW);
            float4 v3 = *(const float4*)(src + 3*HW);
            u16* dst = Bs + (g*4)*40 + q*4;
            *(ushort4*)(dst)       = make_ushort4(f2bf(v0.x), f2bf(v1.x), f2bf(v2.x), f2bf(v3.x));
            *(ushort4*)(dst + 40)  = make_ushort4(f2bf(v0.y), f2bf(v1.y), f2bf(v2.y), f2bf(v3.y));
            *(ushort4*)(dst + 80)  = make_ushort4(f2bf(v0.z), f2bf(v1.z), f2bf(v2.z), f2bf(v3.z));
            *(ushort4*)(dst + 120) = make_ushort4(f2bf(v0.w), f2bf(v1.w), f2bf(v2.w), f2bf(v3.w));
        }
        __syncthreads();
        #pragma unroll
        for (int kk = 0; kk < 2; ++kk) {
            bf16x8 a0 = *(const bf16x8*)(As + (l31     )*40 + kk*16 + lh*8);
            bf16x8 a1 = *(const bf16x8*)(As + (l31 + 32)*40 + kk*16 + lh*8);
            #pragma unroll
            for (int p = 0; p < 2; ++p) {
                bf16x8 bb = *(const bf16x8*)(Bs + (wv*64 + p*32 + l31)*40 + kk*16 + lh*8);
                acc[0][p] = __builtin_amdgcn_mfma_f32_32x32x16_bf16(a0, bb, acc[0][p], 0, 0, 0);
                acc[1][p] = __builtin_amdgcn_mfma_f32_32x32x16_bf16(a1, bb, acc[1][p], 0, 0, 0);
            }
        }
        __syncthreads();
    }

    #pragma unroll
    for (int cf = 0; cf < 2; ++cf) {
        #pragma unroll
        for (int p = 0; p < 2; ++p) {
            int pos = hw0 + wv*64 + p*32 + l31;
            #pragma unroll
            for (int reg = 0; reg < 16; ++reg) {
                int row = (reg & 3) + 8*(reg >> 2) + 4*lh;
                int co  = co0 + cf*32 + row;
                comp[(long)n*CHW + (long)co*HW + pos] = f2bf(acc[cf][p][reg] + b[co]);
            }
        }
    }
}

// ---------------------------------------------------------------------------
// K2: fused 3x3 convs, bf16 MFMA implicit GEMM.  (r16: exact restore of the
// best-measured config, 240 us: r9 tile + A/B reg-prefetch + XCD remap.)
// block = 64co x 256pos (2 rows), 4 waves of 64co x 64pos, acc[2][2] = 64 AGPR.
// LDS: As[64][152] (304B stride), Bs[4][132][16] XOR-swizzled.
// ---------------------------------------------------------------------------
__global__ __launch_bounds__(256, 3)
void conv3x3_mfma_kernel(const u16* __restrict__ comp, const u16* __restrict__ wcat,
                         const float* __restrict__ xin,
                         const float* __restrict__ b_hp, const float* __restrict__ b_res,
                         const float* __restrict__ b_mul,
                         float* __restrict__ out, float* __restrict__ filt_raw)
{
    __shared__ u16 As[64 * 152];        // 19,456 B
    __shared__ u16 Bs[4 * 132 * 16];    // 16,896 B  (total 36,352 B)

    // ---- XCD-aware remap (2304 blocks, %8==0 -> bijective)
    const int id  = blockIdx.x + 256 * blockIdx.y;
    const int xcd = id & 7;
    const int rr_ = id >> 3;            // 0..287
    const int ct  = rr_ % 9;            // co-tile 0..8
    const int pt  = (xcd << 5) + rr_ / 9; // pos-tile 0..255

    const int n   = pt >> 6;
    const int y0  = (pt & 63) * 2;
    const int co0 = ct * 64;

    const int tid  = threadIdx.x;
    const int wv   = tid >> 6;
    const int lane = tid & 63;
    const int l31  = lane & 31;
    const int lh   = lane >> 5;
    const int row  = wv & 1;            // output row within block
    const int ch   = wv >> 1;           // column half (0/1)

    // zero Bs (pads + OOB rows stay zero; swizzle bijective so all-zero ok)
    for (int i = tid; i < 4*132*16/2; i += 256) ((int*)Bs)[i] = 0;

    f32x16 acc[2][2];
    #pragma unroll
    for (int cf = 0; cf < 2; ++cf)
        #pragma unroll
        for (int p = 0; p < 2; ++p)
            #pragma unroll
            for (int e = 0; e < 16; ++e) acc[cf][p][e] = 0.f;

    const u16* wbase = wcat + (long)co0 * 2304;

    // ---- A staging coords: 1152 16B-items; item l: co=l/18, s=l%18 (tap=s>>1, half=s&1)
    const u16* asrc[5]; u16* adst[5]; bool avld[5];
    #pragma unroll
    for (int r = 0; r < 5; ++r) {
        int l = tid + 256*r;
        avld[r] = (l < 1152);
        int ll = avld[r] ? l : 0;
        int co = ll / 18, s = ll - co*18;
        asrc[r] = wbase + co*2304 + (s >> 1)*256 + (s & 1)*8;
        adst[r] = As + co*152 + s*8;
    }

    // ---- B staging coords: wave wv stages patch row wv (y = y0-1+wv)
    const int byy = y0 - 1 + wv;
    const bool bv = (byy >= 0 && byy < H);
    const u16* bsrc = comp + ((long)n*C + lh*8)*HW + (bv ? byy : 0)*W + l31*4;

    __syncthreads();                      // Bs zero-fill visible

    // prologue: prefetch chunk 0 A and B into registers
    ushort8 pa[5];
    #pragma unroll
    for (int r = 0; r < 5; ++r)
        if (avld[r]) pa[r] = *(const ushort8*)(asrc[r]);
    ushort4 pb[8];
    if (bv) {
        #pragma unroll
        for (int j = 0; j < 8; ++j) pb[j] = *(const ushort4*)(bsrc + (long)j*HW);
    }

    for (int c = 0; c < 16; ++c) {
        // ---- stage A(c): write prefetched regs
        #pragma unroll
        for (int r = 0; r < 5; ++r)
            if (avld[r]) *(ushort8*)(adst[r]) = pa[r];
        // ---- stage B(c): write prefetched regs, transposed, swizzled
        if (bv) {
            #pragma unroll
            for (int cw = 0; cw < 4; ++cw) {
                ushort8 v;
                #pragma unroll
                for (int j = 0; j < 8; ++j) v[j] = ((const u16*)&pb[j])[cw];
                int byteoff = ((wv*132 + l31*4 + 1 + cw) << 5) + (lh << 4);
                *(ushort8*)((char*)Bs + swzB(byteoff)) = v;
            }
        }
        __syncthreads();
        // ---- prefetch A(c+1), B(c+1): latency hides under the MFMA phase
        if (c < 15) {
            const int c0n = (c + 1) * 16;
            #pragma unroll
            for (int r = 0; r < 5; ++r)
                if (avld[r]) pa[r] = *(const ushort8*)(asrc[r] + c0n);
            if (bv) {
                const u16* s = bsrc + (long)c0n*HW;
                #pragma unroll
                for (int j = 0; j < 8; ++j) pb[j] = *(const ushort4*)(s + (long)j*HW);
            }
        }
        // ---- MFMA: per tap: 2 A-frags, 2 B-frags, 4 MFMA
        #pragma unroll
        for (int tap = 0; tap < 9; ++tap) {
            const int kh = tap / 3, kw = tap - kh*3;
            bf16x8 a0 = *(const bf16x8*)((const char*)As + l31*304      + tap*32 + lh*16);
            bf16x8 a1 = *(const bf16x8*)((const char*)As + (l31+32)*304 + tap*32 + lh*16);
            #pragma unroll
            for (int p = 0; p < 2; ++p) {
                int byteoff = (((row + kh)*132 + ch*64 + p*32 + l31 + kw) << 5) + (lh << 4);
                bf16x8 bb = *(const bf16x8*)((const char*)Bs + swzB(byteoff));
                acc[0][p] = __builtin_amdgcn_mfma_f32_32x32x16_bf16(a0, bb, acc[0][p], 0, 0, 0);
                acc[1][p] = __builtin_amdgcn_mfma_f32_32x32x16_bf16(a1, bb, acc[1][p], 0, 0, 0);
            }
        }
        __syncthreads();
    }

    // ---- epilogue: D col = lane&31 (pos), row = (reg&3)+8*(reg>>2)+4*(lane>>5) (co)
    const int yrow = y0 + row;
    #pragma unroll
    for (int cf = 0; cf < 2; ++cf) {
        #pragma unroll
        for (int p = 0; p < 2; ++p) {
            int xx = ch*64 + p*32 + l31;
            #pragma unroll
            for (int reg = 0; reg < 16; ++reg) {
                int rw = (reg & 3) + 8*(reg >> 2) + 4*lh;
                int co = co0 + cf*32 + rw;
                float v = acc[cf][p][reg];
                if (co < 9) {
                    filt_raw[((long)n*9 + co)*HW + yrow*W + xx] = v + b_hp[co];
                } else if (co < 265) {
                    int cc = co - 9;
                    long idx = (long)n*CHW + (long)cc*HW + yrow*W + xx;
                    out[(long)TOT + idx] = xin[idx] + v + b_res[cc];
                } else if (co < 521) {
                    int cc = co - 265;
                    long idx = (long)n*CHW + (long)cc*HW + yrow*W + xx;
                    out[2L*TOT + idx] = xin[idx] * (v + b_mul[cc]);
                }
            }
        }
    }
}

// ---------------------------------------------------------------------------
// K3: softmax*hamming renorm + 3x3 carafe + feat_hp = x - carafe (float4)
// r16: 2 output rows per block -- 4 x-rows read per 2 rows written (was 3
// per 1, 33% less x traffic). 512 blocks = n x 64 row-pairs x 2 ch-halves;
// thread = 16 channels x 4 cols x 2 rows. XCD remap (512%8==0).
// ---------------------------------------------------------------------------
__global__ __launch_bounds__(256)
void carafe_hp_kernel(const float* __restrict__ x, const float* __restrict__ filt_raw,
                      const float* __restrict__ ham, float* __restrict__ out)
{
    const int id  = blockIdx.x;
    const int pt  = ((id & 7) << 6) + (id >> 3);  // xcd*64 + r, bijective on [0,512)
    const int n   = pt >> 7;                      // 128 tiles per image
    const int rem = pt & 127;
    const int yp  = rem & 63;                     // row pair
    const int chh = rem >> 6;                     // channel half (0/1)
    const int y0  = yp * 2;

    const int pg = threadIdx.x & 31;
    const int cs = threadIdx.x >> 5;              // 8 slices x 16 channels
    const int x0 = pg * 4;
    const int c0 = chh*128 + cs*16;

    // normalized carafe weights for both rows
    float4 wt[2][9];
    #pragma unroll
    for (int r = 0; r < 2; ++r) {
        const float* fr = filt_raw + (long)n*9*HW + (y0 + r)*W + x0;
        #pragma unroll
        for (int t = 0; t < 9; ++t) wt[r][t] = *(const float4*)(fr + t*HW);
        float4 mx = wt[r][0];
        #pragma unroll
        for (int t = 1; t < 9; ++t) {
            mx.x = fmaxf(mx.x, wt[r][t].x); mx.y = fmaxf(mx.y, wt[r][t].y);
            mx.z = fmaxf(mx.z, wt[r][t].z); mx.w = fmaxf(mx.w, wt[r][t].w);
        }
        float4 s = make_float4(0,0,0,0);
        #pragma unroll
        for (int t = 0; t < 9; ++t) {
            float hm = ham[t];
            wt[r][t].x = expf(wt[r][t].x - mx.x) * hm; s.x += wt[r][t].x;
            wt[r][t].y = expf(wt[r][t].y - mx.y) * hm; s.y += wt[r][t].y;
            wt[r][t].z = expf(wt[r][t].z - mx.z) * hm; s.z += wt[r][t].z;
            wt[r][t].w = expf(wt[r][t].w - mx.w) * hm; s.w += wt[r][t].w;
        }
        float4 inv = make_float4(1.f/s.x, 1.f/s.y, 1.f/s.z, 1.f/s.w);
        #pragma unroll
        for (int t = 0; t < 9; ++t) {
            wt[r][t].x *= inv.x; wt[r][t].y *= inv.y;
            wt[r][t].z *= inv.z; wt[r][t].w *= inv.w;
        }
    }

    const float* xb = x   + (long)n*CHW + (long)y0*W + x0;
    float*       ob = out + (long)n*CHW + (long)y0*W + x0;

    for (int i = 0; i < 16; ++i) {
        int c = c0 + i;
        const float* xc = xb + (long)c*HW;
        float rr[4][6];                  // rows y0-1 .. y0+2
        #pragma unroll
        for (int dh = 0; dh < 4; ++dh) {
            int yy = y0 - 1 + dh;
            if (yy >= 0 && yy < H) {
                const float* p = xc + (dh-1)*W;
                float4 v = *(const float4*)p;
                rr[dh][0] = (x0 > 0)     ? p[-1] : 0.f;
                rr[dh][1] = v.x; rr[dh][2] = v.y; rr[dh][3] = v.z; rr[dh][4] = v.w;
                rr[dh][5] = (x0 + 4 < W) ? p[4]  : 0.f;
            } else {
                #pragma unroll
                for (int j = 0; j < 6; ++j) rr[dh][j] = 0.f;
            }
        }
        #pragma unroll
        for (int r = 0; r < 2; ++r) {
            float4 a = make_float4(0,0,0,0);
            #pragma unroll
            for (int dh = 0; dh < 3; ++dh)
                #pragma unroll
                for (int kw = 0; kw < 3; ++kw) {
                    float4 wv = wt[r][dh*3+kw];
                    a.x += wv.x * rr[r+dh][kw];
                    a.y += wv.y * rr[r+dh][kw+1];
                    a.z += wv.z * rr[r+dh][kw+2];
                    a.w += wv.w * rr[r+dh][kw+3];
                }
            float4 o;
            o.x = rr[r+1][1] - a.x; o.y = rr[r+1][2] - a.y;
            o.z = rr[r+1][3] - a.z; o.w = rr[r+1][4] - a.w;
            *(float4*)(ob + (long)c*HW + r*W) = o;
        }
    }
}

// ---------------------------------------------------------------------------
extern "C" void kernel_launch(void* const* d_in, const int* in_sizes, int n_in,
                              void* d_out, int out_size, void* d_ws, size_t ws_size,
                              hipStream_t stream)
{
    const float* x      = (const float*)d_in[0];
    const float* w_comp = (const float*)d_in[1];
    const float* b_comp = (const float*)d_in[2];
    const float* w_hp   = (const float*)d_in[3];
    const float* b_hp   = (const float*)d_in[4];
    const float* w_res  = (const float*)d_in[5];
    const float* b_res  = (const float*)d_in[6];
    const float* w_mul  = (const float*)d_in[7];
    const float* b_mul  = (const float*)d_in[8];
    const float* ham    = (const float*)d_in[9];
    float* out = (float*)d_out;

    u16*   comp = (u16*)d_ws;
    float* filt = (float*)((char*)d_ws + (size_t)TOT*2);
    u16*   wcat = (u16*)((char*)d_ws + (size_t)TOT*2 + 2359296);
    u16*   wbf  = (u16*)((char*)d_ws + (size_t)TOT*2 + 2359296 + 2654208);

    const int NW = 576*2304;
    prep_w_kernel<<<(NW + 65536 + 255)/256, 256, 0, stream>>>(w_hp, w_res, w_mul, w_comp, wcat, wbf);
    conv1x1_mfma_kernel<<<dim3(256, 4), 256, 0, stream>>>(x, wbf, b_comp, comp);
    conv3x3_mfma_kernel<<<dim3(NIMG*H/2, 9), 256, 0, stream>>>(
        comp, wcat, x, b_hp, b_res, b_mul, out, filt);
    carafe_hp_kernel<<<512, 256, 0, stream>>>(x, filt, ham, out);
}